// Round 4
// baseline (170.560 us; speedup 1.0000x reference)
//
#include <hip/hip_runtime.h>

// out[b,n] = prod_d psi((x[b,d]-c[n,d])/s[n,d]),  psi(z)=(1-z^2)exp(-z^2/2)
// Factorization: per 16-d group, prod psi = [prod(1-z^2)] * exp2(-0.7213*sum z^2)
// (per-lane partial product <= 80^8 ~ 1.7e15, merged ~3e30 < 3.4e38 fp32 max).
// fp32-only: any f16 path puts ~1e-3 rel error into the exponent.
//
// R12: R11 + register prefetch of pp one chunk ahead. Post-mortems:
// R7==R8 (occupancy-insensitive), R11==R8 (scalar-x path not the stall),
// R9/R10 (LDS pp staging under cap-64 = spill disaster). Remaining
// suspect for the ~2x gap over the ~14-19us issue floor: 4 exposed
// ~200-400cy L2 convoys per wave -- each h-chunk's 8 pp dwordx4 gate all
// of that chunk's compute (compiler emits loads + vmcnt(0) at chunk top;
// waves pace in loose lockstep so interleaving hides little, matching
// occupancy-insensitivity). Fix: issue chunk h+1's 8 loads right after
// chunk h's params are consumed into P[] -- ~1400cy of bi-loop compute
// covers the latency. No in-loop barriers, pp NOT in LDS, cap 128.
// Also: v4f/v2f ext_vector typing + shufflevector aliasing so cp/rs/x
// pk-pairs are register renames, not repack movs.
// VGPR budget: q 32 + P ~32(aliased) + X 16 + acc 8 + temps ~16 = ~105.

#define DD 64
#define BSTRIP 8    // b rows per wave; 4 waves -> 32 rows per block

typedef float v2f __attribute__((ext_vector_type(2)));
typedef float v4f __attribute__((ext_vector_type(4)));

__global__ __launch_bounds__(256)
void prep(const float* __restrict__ c, const float* __restrict__ s,
          float4* __restrict__ pp, int N) {
    int i = blockIdx.x * 256 + threadIdx.x;   // over (DD/2)*N
    if (i < (DD / 2) * N) {
        int dp = i / N, n = i - dp * N;
        float r0 = 1.0f / s[n * DD + 2 * dp];
        float r1 = 1.0f / s[n * DD + 2 * dp + 1];
        pp[i] = make_float4(c[n * DD + 2 * dp] * r0,
                            c[n * DD + 2 * dp + 1] * r1, r0, r1);
    }
}

__global__ __launch_bounds__(256, 2)
void wavelet_kernel(const float* __restrict__ x,
                    const float4* __restrict__ pp,
                    float* __restrict__ out, int B, int N) {
    __shared__ v4f xls[32 * 16];   // block's x strip: 32 rows x 16 qwords, 8 KB

    int t = threadIdx.x;
    int lane = t & 63;
    int wv = __builtin_amdgcn_readfirstlane(t >> 6);   // wave-uniform
    int n0 = blockIdx.y * 64;
    int n = n0 + lane;                                 // lane-private column
    int bblk = blockIdx.x * 32;                        // block's 32 b rows

    // one-time cooperative stage of x[bblk..bblk+31][0..63]:
    // 512 qwords, 2 per thread, consecutive t -> consecutive 16 B (coalesced)
    {
        const v4f* xg = (const v4f*)(x + (size_t)bblk * DD);
        xls[t] = xg[t];
        xls[t + 256] = xg[t + 256];
    }

    const v4f* pcol = (const v4f*)pp + n;   // pp[dp*N + n], lane-coalesced

    // prefetch chunk 0 params before the barrier
    v4f q[8];
#pragma unroll
    for (int i = 0; i < 8; ++i) q[i] = pcol[(size_t)i * N];

    __syncthreads();   // the only barrier

    float acc[BSTRIP];
#pragma unroll
    for (int bi = 0; bi < BSTRIP; ++bi) acc[bi] = 1.0f;

    // one d-pair: z=(x-c)/s via fma, w=z^2, p*=(1-w), s2+=w
#define PAIR(Q, XV)                                                           \
    {                                                                         \
        v2f cp = __builtin_shufflevector(Q, Q, 0, 1);                         \
        v2f rv = __builtin_shufflevector(Q, Q, 2, 3);                         \
        v2f z = __builtin_elementwise_fma(XV, rv, -cp);                       \
        v2f w = z * z;                                                        \
        p = __builtin_elementwise_fma(-w, p, p);                              \
        s2 += w;                                                              \
    }
#define LO(V) __builtin_shufflevector(V, V, 0, 1)
#define HI(V) __builtin_shufflevector(V, V, 2, 3)

#pragma unroll
    for (int h = 0; h < 4; ++h) {          // 4 chunks of 16 d (= overflow group)
        // consume the prefetched params (register rename, no copies)
        v4f P[8];
#pragma unroll
        for (int i = 0; i < 8; ++i) P[i] = q[i];
        // issue next chunk's loads now; ~1400cy of compute below covers them
        if (h < 3) {
#pragma unroll
            for (int i = 0; i < 8; ++i)
                q[i] = pcol[(size_t)((h + 1) * 8 + i) * N];
        }

#pragma unroll
        for (int bi = 0; bi < BSTRIP; ++bi) {
            // x slice: wave-uniform LDS address -> broadcast ds_read_b128
            const v4f* xq = &xls[(wv * BSTRIP + bi) * 16 + h * 4];
            v4f X0 = xq[0];
            v4f X1 = xq[1];
            v4f X2 = xq[2];
            v4f X3 = xq[3];
            v2f p  = {1.0f, 1.0f};
            v2f s2 = {0.0f, 0.0f};
            PAIR(P[0], LO(X0)) PAIR(P[1], HI(X0))
            PAIR(P[2], LO(X1)) PAIR(P[3], HI(X1))
            PAIR(P[4], LO(X2)) PAIR(P[5], HI(X2))
            PAIR(P[6], LO(X3)) PAIR(P[7], HI(X3))
            // exp(-0.5*s) = exp2(-0.72134752*s), one per 16-d group
            acc[bi] *= (p.x * p.y) *
                       __builtin_exp2f(-0.72134752f * (s2.x + s2.y));
        }
    }

    // stores: lanes = consecutive n -> coalesced
#pragma unroll
    for (int bi = 0; bi < BSTRIP; ++bi)
        out[(size_t)(bblk + wv * BSTRIP + bi) * N + n] = acc[bi];
#undef PAIR
#undef LO
#undef HI
}

extern "C" void kernel_launch(void* const* d_in, const int* in_sizes, int n_in,
                              void* d_out, int out_size, void* d_ws, size_t ws_size,
                              hipStream_t stream) {
    const float* x = (const float*)d_in[0];
    const float* c = (const float*)d_in[1];
    const float* s = (const float*)d_in[2];
    float* out = (float*)d_out;

    int B = in_sizes[0] / DD;    // 8192
    int N = in_sizes[1] / DD;    // 512

    float4* pp = (float4*)d_ws;  // (DD/2)*N*16 B = 256 KB

    int total = (DD / 2) * N;
    prep<<<(total + 255) / 256, 256, 0, stream>>>(c, s, pp, N);

    // grid: x = b strips of 32 rows (4 waves x 8), y = n/64
    dim3 grid(B / 32, N / 64);   // 256 x 8 = 2048 blocks
    wavelet_kernel<<<grid, 256, 0, stream>>>(x, pp, out, B, N);
}

// Round 5
// 88.876 us; speedup vs baseline: 1.9191x; 1.9191x over previous
//
#include <hip/hip_runtime.h>

// out[b,n] = prod_d psi((x[b,d]-c[n,d])/s[n,d]),  psi(z)=(1-z^2)exp(-z^2/2)
// Factorization: per 8-d group, prod psi = [prod(1-z^2)] * exp2(-0.7213*sum z^2).
// Per-slot partial product <= 80^4 = 4.1e7; merged (p.x*p.y) <= 1.7e15; after
// the exp2 damp each group factor is a psi-product <= 1 -> acc in [0,1].
// fp32-only: any f16 path puts ~1e-3 rel error into the exponent.
//
// R13: register-budgeted software pipeline (the R12 theory, spill-proofed).
// Post-mortems: R9/R10/R12 all spilled (phantom 250-460 MB scratch traffic,
// VGPR pinned at cap) -- prefetch was never cleanly tested. R7==R8==R11
// (~41-43us warm wavelet vs ~14us issue floor) regardless of occupancy or
// x-path -> suspect exposed load latency at every consume point, identical
// in all variants. This version:
//  - pp in named A0-3/B0-3 v4f ping-pong (32 VGPR params, = R11, not R12's 64)
//  - outer loop '#pragma unroll 1', body unrolled x2 (pf B / compute A /
//    pf A' / compute B): static buffer roles, no cross-iteration hoisting,
//    natural vmcnt(4) waits (B in flight while A consumed)
//  - x ds_reads prefetched one bi ahead (Xa/Xb compute, Xc/Xd load)
//  - exp2 merge per 8 dims (+~2% issue, R10-validated numerics)
//  - hh=3's dead prefetch reads pp[256K..295K) inside the 256MB ws: harmless
//  - prep transposed: coalesced float2 reads, scatter on the write side
// VGPR tally: A/B 32 + X 16 + acc 8 + p/s2 4 + addr ~20 + temps ~10 = ~90 <128.

#define DD 64
#define BSTRIP 8    // b rows per wave; 4 waves -> 32 rows per block

typedef float v2f __attribute__((ext_vector_type(2)));
typedef float v4f __attribute__((ext_vector_type(4)));

__global__ __launch_bounds__(256)
void prep(const float* __restrict__ c, const float* __restrict__ s,
          float4* __restrict__ pp, int N) {
    int i = blockIdx.x * 256 + threadIdx.x;   // over N*(DD/2)
    if (i < N * (DD / 2)) {
        int n = i >> 5, dp = i & 31;          // consecutive i -> consecutive dp
        float2 cc = ((const float2*)c)[i];    // coalesced dwordx2
        float2 ss = ((const float2*)s)[i];
        float r0 = 1.0f / ss.x;
        float r1 = 1.0f / ss.y;
        // scatter on the (stall-free) write side: pp[dp][n]
        pp[dp * N + n] = make_float4(cc.x * r0, cc.y * r1, r0, r1);
    }
}

__global__ __launch_bounds__(256, 2)
void wavelet_kernel(const float* __restrict__ x,
                    const float4* __restrict__ pp,
                    float* __restrict__ out, int B, int N) {
    __shared__ v4f xls[32 * 16];   // block's x strip: 32 rows x 16 qwords, 8 KB

    int t = threadIdx.x;
    int lane = t & 63;
    int wv = __builtin_amdgcn_readfirstlane(t >> 6);   // wave-uniform
    int n0 = blockIdx.y * 64;
    int n = n0 + lane;                                 // lane-private column
    int bblk = blockIdx.x * 32;                        // block's 32 b rows
    int row = wv * BSTRIP;                             // wave's first xls row

    // one-time cooperative stage of x[bblk..bblk+31][0..63] (coalesced)
    {
        const v4f* xg = (const v4f*)(x + (size_t)bblk * DD);
        xls[t] = xg[t];
        xls[t + 256] = xg[t + 256];
    }

    const v4f* pcol = (const v4f*)pp + n;   // pp[dp*N + n], lane-coalesced

    // preload half-chunk 0 params (dims 0..7 = dp rows 0..3)
    v4f A0 = pcol[0 * (size_t)N];
    v4f A1 = pcol[1 * (size_t)N];
    v4f A2 = pcol[2 * (size_t)N];
    v4f A3 = pcol[3 * (size_t)N];

    __syncthreads();   // xls ready (the only barrier)

    float acc[BSTRIP];
#pragma unroll
    for (int bi = 0; bi < BSTRIP; ++bi) acc[bi] = 1.0f;

#define LO(V) __builtin_shufflevector(V, V, 0, 1)
#define HI(V) __builtin_shufflevector(V, V, 2, 3)
    // one d-pair: z=(x-c)/s via fma, w=z^2, p*=(1-w), s2+=w
#define PAIR(Q, XV)                                                           \
    {                                                                         \
        v2f cp = __builtin_shufflevector(Q, Q, 0, 1);                         \
        v2f rv = __builtin_shufflevector(Q, Q, 2, 3);                         \
        v2f z = __builtin_elementwise_fma(XV, rv, -cp);                       \
        v2f w = z * z;                                                        \
        p = __builtin_elementwise_fma(-w, p, p);                              \
        s2 += w;                                                              \
    }
    // 8 dims with params P0..P3; x prefetched one bi ahead (broadcast reads)
#define COMPUTE_HALF(P0, P1, P2, P3, HB)                                      \
    {                                                                         \
        int xb = row * 16 + 2 * (HB);                                         \
        v4f Xa = xls[xb];                                                     \
        v4f Xb = xls[xb + 1];                                                 \
        _Pragma("unroll")                                                     \
        for (int bi = 0; bi < BSTRIP; ++bi) {                                 \
            v4f Xc = Xa, Xd = Xb;                                             \
            if (bi < BSTRIP - 1) {                                            \
                Xc = xls[xb + (bi + 1) * 16];                                 \
                Xd = xls[xb + (bi + 1) * 16 + 1];                             \
            }                                                                 \
            v2f p = {1.0f, 1.0f};                                             \
            v2f s2 = {0.0f, 0.0f};                                            \
            PAIR(P0, LO(Xa)) PAIR(P1, HI(Xa))                                 \
            PAIR(P2, LO(Xb)) PAIR(P3, HI(Xb))                                 \
            acc[bi] *= (p.x * p.y) *                                          \
                       __builtin_exp2f(-0.72134752f * (s2.x + s2.y));         \
            Xa = Xc; Xb = Xd;                                                 \
        }                                                                     \
    }

#pragma unroll 1
    for (int hh = 0; hh < 4; ++hh) {       // 2 half-chunks (16 dims) per iter
        int h1 = 2 * hh + 1, h2 = 2 * hh + 2;
        // prefetch half h1 into B (4 loads in flight over compute A)
        v4f B0 = pcol[(size_t)(4 * h1 + 0) * N];
        v4f B1 = pcol[(size_t)(4 * h1 + 1) * N];
        v4f B2 = pcol[(size_t)(4 * h1 + 2) * N];
        v4f B3 = pcol[(size_t)(4 * h1 + 3) * N];

        COMPUTE_HALF(A0, A1, A2, A3, 2 * hh)

        // prefetch half h2 into A (hh=3 reads dead-but-safe ws bytes)
        A0 = pcol[(size_t)(4 * h2 + 0) * N];
        A1 = pcol[(size_t)(4 * h2 + 1) * N];
        A2 = pcol[(size_t)(4 * h2 + 2) * N];
        A3 = pcol[(size_t)(4 * h2 + 3) * N];

        COMPUTE_HALF(B0, B1, B2, B3, h1)
    }

    // stores: lanes = consecutive n -> coalesced
#pragma unroll
    for (int bi = 0; bi < BSTRIP; ++bi)
        out[(size_t)(bblk + row + bi) * N + n] = acc[bi];
#undef COMPUTE_HALF
#undef PAIR
#undef LO
#undef HI
}

extern "C" void kernel_launch(void* const* d_in, const int* in_sizes, int n_in,
                              void* d_out, int out_size, void* d_ws, size_t ws_size,
                              hipStream_t stream) {
    const float* x = (const float*)d_in[0];
    const float* c = (const float*)d_in[1];
    const float* s = (const float*)d_in[2];
    float* out = (float*)d_out;

    int B = in_sizes[0] / DD;    // 8192
    int N = in_sizes[1] / DD;    // 512

    float4* pp = (float4*)d_ws;  // (DD/2)*N*16 B = 256 KB

    int total = N * (DD / 2);
    prep<<<(total + 255) / 256, 256, 0, stream>>>(c, s, pp, N);

    // grid: x = b strips of 32 rows (4 waves x 8), y = n/64
    dim3 grid(B / 32, N / 64);   // 256 x 8 = 2048 blocks
    wavelet_kernel<<<grid, 256, 0, stream>>>(x, pp, out, B, N);
}